// Round 2
// baseline (194.452 us; speedup 1.0000x reference)
//
#include <hip/hip_runtime.h>
#include <hip/hip_bf16.h>

#define IN_FT 128
#define OUT_FT 128

typedef __bf16 bf16x8 __attribute__((ext_vector_type(8)));
typedef float f32x4 __attribute__((ext_vector_type(4)));

// ---------------------------------------------------------------------------
// Kernel 1: build CSR row pointers from sorted edge_dst.
// rowptr[v] = first edge index e with edge_dst[e] >= v ; rowptr[N] = E.
// ---------------------------------------------------------------------------
__global__ void build_rowptr(const int* __restrict__ edst,
                             int* __restrict__ rowptr, int E, int N) {
    int e = blockIdx.x * blockDim.x + threadIdx.x;
    if (e >= E) return;
    int d = edst[e];
    int prev = (e == 0) ? -1 : edst[e - 1];
    for (int v = prev + 1; v <= d; ++v) rowptr[v] = e;
    if (e == E - 1) {
        for (int v = d + 1; v <= N; ++v) rowptr[v] = E;
    }
}

// ---------------------------------------------------------------------------
// Kernel 2: weighted neighbor aggregation (fp32 in, fp32 accum), writing the
// fused  hb[v] = [ bf16(x[v]) | bf16(emb[v]) ]  row of the concat GEMM input.
// One block per node, thread = feature.
// ---------------------------------------------------------------------------
__global__ __launch_bounds__(128) void spmm_node(
    const float* __restrict__ x,          // [N,128] fp32
    const int* __restrict__ esrc,         // [E]
    const float* __restrict__ ew,         // [E] fp32
    const int* __restrict__ rowptr,       // [N+1]
    __hip_bfloat16* __restrict__ hb) {    // [N,256] bf16 out
    int v = blockIdx.x;
    int f = threadIdx.x;
    int e0 = rowptr[v], e1 = rowptr[v + 1];
    float acc = 0.f;
    for (int e = e0; e < e1; ++e) {
        int s = esrc[e];
        float w = ew[e];
        acc += w * x[(size_t)s * IN_FT + f];
    }
    hb[(size_t)v * 256 + f] = (__hip_bfloat16)x[(size_t)v * IN_FT + f];
    hb[(size_t)v * 256 + 128 + f] = (__hip_bfloat16)acc;
}

// ---------------------------------------------------------------------------
// Kernel 3: swizzle W [256x128] fp32 -> bf16 so that B-fragments for
// mfma 16x16x32 are contiguous 16B chunks:
//   wsw[((k>>3)*128 + n)*8 + (k&7)] = bf16(W[k][n])
// ---------------------------------------------------------------------------
__global__ void swizzle_w(const float* __restrict__ w,
                          __hip_bfloat16* __restrict__ wsw) {
    int idx = blockIdx.x * blockDim.x + threadIdx.x;  // 0..32767
    int k = idx >> 7, n = idx & 127;
    wsw[(((k >> 3) * 128 + n) << 3) + (k & 7)] = (__hip_bfloat16)w[idx];
}

// ---------------------------------------------------------------------------
// Kernel 4: out = relu(hb @ W + b), fp32 output. 64 rows/block, 4 waves x 16
// rows, full 128-col output per wave (8 col tiles), K=256 in 8 steps of 32.
// W (swizzled bf16, 64KB) staged in LDS once per block.
// Verified gfx950 layouts (learn_hip m89/m91/m118):
//   A[m=lane&15][k=(lane>>4)*8+j],  B[k=(lane>>4)*8+j][n=lane&15],
//   C/D: col=lane&15, row=(lane>>4)*4+reg.
// ---------------------------------------------------------------------------
__global__ __launch_bounds__(256) void gemm_relu(
    const __hip_bfloat16* __restrict__ hb,    // [N,256] bf16
    const __hip_bfloat16* __restrict__ wsw,   // [256*128] swizzled bf16
    const float* __restrict__ bias,           // [128] fp32
    float* __restrict__ out,                  // [N,128] fp32
    int N) {
    __shared__ __hip_bfloat16 w_lds[256 * 128];  // 64 KB, swizzled layout
    int t = threadIdx.x;

    // cooperative 16B-chunk load of swizzled W into LDS
    {
        const uint4* src = (const uint4*)wsw;
        uint4* dst = (uint4*)w_lds;
#pragma unroll
        for (int i = 0; i < 16; ++i) dst[t + i * 256] = src[t + i * 256];
    }
    __syncthreads();

    int wave = t >> 6;   // 0..3
    int lane = t & 63;
    int m = lane & 15;
    int quad = lane >> 4;
    int rowbase = blockIdx.x * 64 + wave * 16;
    int row = rowbase + m;
    int rowc = min(row, N - 1);  // clamp for loads; stores guarded

    f32x4 acc[8];
#pragma unroll
    for (int i = 0; i < 8; ++i) acc[i] = (f32x4)(0.f);

#pragma unroll
    for (int ks = 0; ks < 8; ++ks) {
        int kk = ks * 32 + quad * 8;
        bf16x8 afrag = *(const bf16x8*)(hb + (size_t)rowc * 256 + kk);
#pragma unroll
        for (int ct = 0; ct < 8; ++ct) {
            int n = ct * 16 + m;
            bf16x8 bfrag =
                *(const bf16x8*)(&w_lds[((((ks << 2) + quad) * 128 + n) << 3)]);
            acc[ct] = __builtin_amdgcn_mfma_f32_16x16x32_bf16(afrag, bfrag,
                                                              acc[ct], 0, 0, 0);
        }
    }

    // epilogue: D col = lane&15 (in tile), row_in_tile = quad*4 + r
    int orow = rowbase + quad * 4;
#pragma unroll
    for (int ct = 0; ct < 8; ++ct) {
        int col = ct * 16 + m;
        float b = bias[col];
#pragma unroll
        for (int r = 0; r < 4; ++r) {
            int rr = orow + r;
            if (rr < N) {
                float vv = acc[ct][r] + b;
                out[(size_t)rr * 128 + col] = fmaxf(vv, 0.f);
            }
        }
    }
}

// ---------------------------------------------------------------------------
extern "C" void kernel_launch(void* const* d_in, const int* in_sizes, int n_in,
                              void* d_out, int out_size, void* d_ws,
                              size_t ws_size, hipStream_t stream) {
    const float* x = (const float*)d_in[0];
    const int* esrc = (const int*)d_in[1];
    const int* edst = (const int*)d_in[2];
    const float* ew = (const float*)d_in[3];
    const float* w = (const float*)d_in[4];
    const float* bias = (const float*)d_in[5];
    float* out = (float*)d_out;

    int N = in_sizes[0] / IN_FT;
    int E = in_sizes[1];

    // workspace layout
    char* ws = (char*)d_ws;
    __hip_bfloat16* hb = (__hip_bfloat16*)ws;   // N*256*2 B = 25.6 MB
    size_t hb_bytes = (size_t)N * 256 * sizeof(__hip_bfloat16);
    hb_bytes = (hb_bytes + 255) & ~(size_t)255;
    __hip_bfloat16* wsw = (__hip_bfloat16*)(ws + hb_bytes);   // 64 KB
    int* rowptr = (int*)(ws + hb_bytes + 65536);              // (N+1)*4 B

    // 1. CSR row pointers from sorted edge_dst
    build_rowptr<<<(E + 255) / 256, 256, 0, stream>>>(edst, rowptr, E, N);
    // 2. swizzle W (fp32 -> bf16) for MFMA B-fragment layout
    swizzle_w<<<(2 * IN_FT * OUT_FT) / 256, 256, 0, stream>>>(w, wsw);
    // 3. neighbor aggregation + concat row build (bf16)
    spmm_node<<<N, 128, 0, stream>>>(x, esrc, ew, rowptr, hb);
    // 4. fused concat-GEMM + bias + relu (fp32 out)
    gemm_relu<<<(N + 63) / 64, 256, 0, stream>>>(hb, wsw, bias, out, N);
}

// Round 4
// 142.422 us; speedup vs baseline: 1.3653x; 1.3653x over previous
//
#include <hip/hip_runtime.h>
#include <hip/hip_bf16.h>

#define IN_FT 128
#define OUT_FT 128

typedef __bf16 bf16x8 __attribute__((ext_vector_type(8)));
typedef float f32x4 __attribute__((ext_vector_type(4)));

static __device__ __forceinline__ __hip_bfloat162 pack_bf162(float a, float b) {
    __hip_bfloat162 r;
    r.x = __float2bfloat16(a);
    r.y = __float2bfloat16(b);
    return r;
}

// ---------------------------------------------------------------------------
// Kernel 1: build CSR row pointers from sorted edge_dst.
// rowptr[v] = first edge index e with edge_dst[e] >= v ; rowptr[N] = E.
// ---------------------------------------------------------------------------
__global__ void build_rowptr(const int* __restrict__ edst,
                             int* __restrict__ rowptr, int E, int N) {
    int e = blockIdx.x * blockDim.x + threadIdx.x;
    if (e >= E) return;
    int d = edst[e];
    int prev = (e == 0) ? -1 : edst[e - 1];
    for (int v = prev + 1; v <= d; ++v) rowptr[v] = e;
    if (e == E - 1) {
        for (int v = d + 1; v <= N; ++v) rowptr[v] = E;
    }
}

// ---------------------------------------------------------------------------
// Kernel 2: cast x fp32 -> bf16 (xb), 12.8 MB working set for the gather.
// ---------------------------------------------------------------------------
__global__ __launch_bounds__(256) void cast_x(const float* __restrict__ x,
                                              __hip_bfloat162* __restrict__ xb2,
                                              int n2) {
    int i = blockIdx.x * blockDim.x + threadIdx.x;
    if (i >= n2) return;
    float2 v = ((const float2*)x)[i];
    xb2[i] = pack_bf162(v.x, v.y);
}

// ---------------------------------------------------------------------------
// Kernel 3: weighted neighbor aggregation. One WAVE per node, lane = feature
// pair (bf16x2 gather, 256 B per row per wave). Edge loop unrolled x4 with
// wave-uniform scalar prefetch of esrc/ew -> 4 gathers in flight.
// ---------------------------------------------------------------------------
__global__ __launch_bounds__(256) void spmm_node(
    const __hip_bfloat162* __restrict__ xb2,  // [N,64] bf16x2
    const int* __restrict__ esrc,             // [E]
    const float* __restrict__ ew,             // [E] fp32
    const int* __restrict__ rowptr,           // [N+1]
    __hip_bfloat162* __restrict__ eb2,        // [N,64] bf16x2 out
    int N) {
    int wave = threadIdx.x >> 6;
    int lane = threadIdx.x & 63;
    int v = blockIdx.x * 4 + wave;
    if (v >= N) return;
    int e0 = rowptr[v], e1 = rowptr[v + 1];
    float a0 = 0.f, a1 = 0.f;
    int e = e0;
    for (; e + 4 <= e1; e += 4) {
        int s0 = esrc[e], s1 = esrc[e + 1], s2 = esrc[e + 2], s3 = esrc[e + 3];
        float w0 = ew[e], w1 = ew[e + 1], w2 = ew[e + 2], w3 = ew[e + 3];
        __hip_bfloat162 p0 = xb2[(size_t)s0 * 64 + lane];
        __hip_bfloat162 p1 = xb2[(size_t)s1 * 64 + lane];
        __hip_bfloat162 p2 = xb2[(size_t)s2 * 64 + lane];
        __hip_bfloat162 p3 = xb2[(size_t)s3 * 64 + lane];
        a0 += w0 * __bfloat162float(p0.x) + w1 * __bfloat162float(p1.x) +
              w2 * __bfloat162float(p2.x) + w3 * __bfloat162float(p3.x);
        a1 += w0 * __bfloat162float(p0.y) + w1 * __bfloat162float(p1.y) +
              w2 * __bfloat162float(p2.y) + w3 * __bfloat162float(p3.y);
    }
    for (; e < e1; ++e) {
        int s = esrc[e];
        float w = ew[e];
        __hip_bfloat162 p = xb2[(size_t)s * 64 + lane];
        a0 += w * __bfloat162float(p.x);
        a1 += w * __bfloat162float(p.y);
    }
    eb2[(size_t)v * 64 + lane] = pack_bf162(a0, a1);
}

// ---------------------------------------------------------------------------
// Kernel 4: swizzle W [256x128] fp32 -> bf16 so that B-fragments for
// mfma 16x16x32 are contiguous 16B chunks:
//   wsw[((k>>3)*128 + n)*8 + (k&7)] = bf16(W[k][n])
// ---------------------------------------------------------------------------
__global__ void swizzle_w(const float* __restrict__ w,
                          __hip_bfloat16* __restrict__ wsw) {
    int idx = blockIdx.x * blockDim.x + threadIdx.x;  // 0..32767
    int k = idx >> 7, n = idx & 127;
    wsw[(((k >> 3) * 128 + n) << 3) + (k & 7)] = (__hip_bfloat16)w[idx];
}

// ---------------------------------------------------------------------------
// Kernel 5: out = relu([xb | eb] @ W + b), fp32 out. Register-resident B:
// each wave holds B-frags for 64 cols x K=256 (128 VGPR), grid-strides over
// 16-row tiles. No LDS, no barriers. Waves {0,1}/{2,3} pair on a row tile
// (col halves), so A rows are read twice but the 2nd hits L1.
// A layout: A[m=lane&15][k=(lane>>4)*8+j]; C/D: col=lane&15, row=quad*4+r.
// ---------------------------------------------------------------------------
__global__ __launch_bounds__(256, 2) void gemm_relu(
    const __hip_bfloat16* __restrict__ xb,   // [N,128] bf16
    const __hip_bfloat16* __restrict__ eb,   // [N,128] bf16
    const __hip_bfloat16* __restrict__ wsw,  // [256*128] swizzled bf16
    const float* __restrict__ bias,          // [128] fp32
    float* __restrict__ out,                 // [N,128] fp32
    int N, int ntiles) {
    int t = threadIdx.x;
    int wave = t >> 6;
    int lane = t & 63;
    int m = lane & 15;
    int quad = lane >> 4;
    int colhalf = wave & 1;          // 0: cols 0..63, 1: cols 64..127
    int colbase = colhalf * 64 + m;  // + ct*16

    // B fragments: 8 ksteps x 4 coltiles, 8 bf16 each = 128 VGPRs
    bf16x8 B[8][4];
#pragma unroll
    for (int ks = 0; ks < 8; ++ks)
#pragma unroll
        for (int ct = 0; ct < 4; ++ct)
            B[ks][ct] = *(const bf16x8*)(wsw +
                (((size_t)((ks << 2) + quad) * 128 + colbase + ct * 16) << 3));

    float bi[4];
#pragma unroll
    for (int ct = 0; ct < 4; ++ct) bi[ct] = bias[colbase + ct * 16];

    for (int tile = blockIdx.x * 2 + (wave >> 1); tile < ntiles;
         tile += gridDim.x * 2) {
        int row = tile * 16 + m;
        int rowc = min(row, N - 1);
        bf16x8 A[8];
#pragma unroll
        for (int ks = 0; ks < 4; ++ks)
            A[ks] = *(const bf16x8*)(xb + (size_t)rowc * 128 + ks * 32 + quad * 8);
#pragma unroll
        for (int ks = 4; ks < 8; ++ks)
            A[ks] = *(const bf16x8*)(eb + (size_t)rowc * 128 + (ks - 4) * 32 + quad * 8);

        f32x4 acc[4];
#pragma unroll
        for (int ct = 0; ct < 4; ++ct) acc[ct] = (f32x4)(0.f);
#pragma unroll
        for (int ks = 0; ks < 8; ++ks)
#pragma unroll
            for (int ct = 0; ct < 4; ++ct)
                acc[ct] = __builtin_amdgcn_mfma_f32_16x16x32_bf16(
                    A[ks], B[ks][ct], acc[ct], 0, 0, 0);

        int orow = tile * 16 + quad * 4;
#pragma unroll
        for (int ct = 0; ct < 4; ++ct) {
            int col = colbase + ct * 16;
#pragma unroll
            for (int r = 0; r < 4; ++r) {
                int rr = orow + r;
                if (rr < N) {
                    float vv = acc[ct][r] + bi[ct];
                    out[(size_t)rr * 128 + col] = fmaxf(vv, 0.f);
                }
            }
        }
    }
}

// ---------------------------------------------------------------------------
extern "C" void kernel_launch(void* const* d_in, const int* in_sizes, int n_in,
                              void* d_out, int out_size, void* d_ws,
                              size_t ws_size, hipStream_t stream) {
    const float* x = (const float*)d_in[0];
    const int* esrc = (const int*)d_in[1];
    const int* edst = (const int*)d_in[2];
    const float* ew = (const float*)d_in[3];
    const float* w = (const float*)d_in[4];
    const float* bias = (const float*)d_in[5];
    float* out = (float*)d_out;

    int N = in_sizes[0] / IN_FT;
    int E = in_sizes[1];

    // workspace layout
    char* ws = (char*)d_ws;
    __hip_bfloat16* xb = (__hip_bfloat16*)ws;  // N*128*2 = 12.8 MB
    size_t xb_bytes = ((size_t)N * IN_FT * 2 + 255) & ~(size_t)255;
    __hip_bfloat16* eb = (__hip_bfloat16*)(ws + xb_bytes);  // 12.8 MB
    size_t eb_bytes = xb_bytes;
    __hip_bfloat16* wsw = (__hip_bfloat16*)(ws + xb_bytes + eb_bytes);  // 64 KB
    int* rowptr = (int*)(ws + xb_bytes + eb_bytes + 65536);  // (N+1)*4

    build_rowptr<<<(E + 255) / 256, 256, 0, stream>>>(edst, rowptr, E, N);
    swizzle_w<<<(2 * IN_FT * OUT_FT) / 256, 256, 0, stream>>>(w, wsw);
    int n2 = N * IN_FT / 2;
    cast_x<<<(n2 + 255) / 256, 256, 0, stream>>>(x, (__hip_bfloat162*)xb, n2);
    spmm_node<<<(N + 3) / 4, 256, 0, stream>>>(
        (const __hip_bfloat162*)xb, esrc, ew, rowptr, (__hip_bfloat162*)eb, N);
    int ntiles = (N + 15) / 16;
    gemm_relu<<<512, 256, 0, stream>>>(xb, eb, wsw, bias, out, N, ntiles);
}

// Round 6
// 140.337 us; speedup vs baseline: 1.3856x; 1.0149x over previous
//
#include <hip/hip_runtime.h>
#include <hip/hip_bf16.h>

#define NFEAT 128   // IN_FT == OUT_FT == 128, K of fused GEMM = 128, N' = 256

typedef __bf16 bf16x8 __attribute__((ext_vector_type(8)));
typedef float f32x4 __attribute__((ext_vector_type(4)));

// ---------------------------------------------------------------------------
// Kernel 1: build CSR row pointers from sorted edge_dst.
// rowptr[v] = first edge index e with edge_dst[e] >= v ; rowptr[N] = E.
// ---------------------------------------------------------------------------
__global__ void build_rowptr(const int* __restrict__ edst,
                             int* __restrict__ rowptr, int E, int N) {
    int e = blockIdx.x * blockDim.x + threadIdx.x;
    if (e >= E) return;
    int d = edst[e];
    int prev = (e == 0) ? -1 : edst[e - 1];
    for (int v = prev + 1; v <= d; ++v) rowptr[v] = e;
    if (e == E - 1) {
        for (int v = d + 1; v <= N; ++v) rowptr[v] = E;
    }
}

// ---------------------------------------------------------------------------
// Kernel 2: swizzle + split W (fp32 [256,128]) into bf16 MFMA-B layout for
// the fused x @ [W1 | W2] GEMM (K=128, 256 output cols):
//   n' < 128 -> W[k][n'] ,  n' >= 128 -> W[128+k][n'-128]
//   wsw[((k>>3)*256 + n')*8 + (k&7)] = bf16(val)   (contiguous 16B B-frags)
// ---------------------------------------------------------------------------
__global__ __launch_bounds__(256) void swizzle_w(const float* __restrict__ w,
                                                 __bf16* __restrict__ wsw) {
    int idx = blockIdx.x * 256 + threadIdx.x;  // 0..32767
    int k = idx >> 8, n = idx & 255;
    int row = (n < 128) ? k : 128 + k;
    int col = n & 127;
    wsw[(((k >> 3) * 256 + n) << 3) + (k & 7)] = (__bf16)w[row * 128 + col];
}

// ---------------------------------------------------------------------------
// Kernel 3: zcat = bf16( x @ [W1 | W2] )   [N, 256]
// cols 0..127 = x@W1 (self term), cols 128..255 = x@W2 (to be aggregated).
// Register-resident B: wave q holds 64 cols x K=128 (64 VGPR); the block's
// 4 waves cover all 256 cols of ONE 16-row tile; grid-stride over tiles.
// (Round-5 bug: slot=wave>>2 with 4 waves left odd tiles uncomputed.)
// A is cast fp32->bf16 in-register. No LDS, no barriers.
// ---------------------------------------------------------------------------
__global__ __launch_bounds__(256, 2) void gemm_z(
    const float* __restrict__ x,     // [N,128] fp32
    const __bf16* __restrict__ wsw,  // swizzled [128,256] bf16
    __bf16* __restrict__ zcat,       // [N,256] bf16 out
    int N, int ntiles) {
    int t = threadIdx.x;
    int q = t >> 6;          // wave = column quarter
    int lane = t & 63;
    int m = lane & 15;
    int quad = lane >> 4;
    int colbase = q * 64 + m;

    bf16x8 B[4][4];  // [kstep][coltile] : 64 VGPRs
#pragma unroll
    for (int ks = 0; ks < 4; ++ks)
#pragma unroll
        for (int ct = 0; ct < 4; ++ct)
            B[ks][ct] = *(const bf16x8*)(wsw +
                (((size_t)(ks * 4 + quad) * 256 + colbase + ct * 16) << 3));

    for (int tile = blockIdx.x; tile < ntiles; tile += gridDim.x) {
        int row = tile * 16 + m;
        int rowc = min(row, N - 1);
        bf16x8 A[4];
#pragma unroll
        for (int ks = 0; ks < 4; ++ks) {
            const float* ap = x + (size_t)rowc * 128 + ks * 32 + quad * 8;
            f32x4 lo = *(const f32x4*)ap;
            f32x4 hi = *(const f32x4*)(ap + 4);
            bf16x8 af;
#pragma unroll
            for (int j = 0; j < 4; ++j) {
                af[j] = (__bf16)lo[j];
                af[j + 4] = (__bf16)hi[j];
            }
            A[ks] = af;
        }

        f32x4 acc[4];
#pragma unroll
        for (int ct = 0; ct < 4; ++ct) acc[ct] = (f32x4)(0.f);
#pragma unroll
        for (int ks = 0; ks < 4; ++ks)
#pragma unroll
            for (int ct = 0; ct < 4; ++ct)
                acc[ct] = __builtin_amdgcn_mfma_f32_16x16x32_bf16(
                    A[ks], B[ks][ct], acc[ct], 0, 0, 0);

        int orow = tile * 16 + quad * 4;  // D: col=lane&15, row=quad*4+r
#pragma unroll
        for (int ct = 0; ct < 4; ++ct) {
            int col = colbase + ct * 16;
#pragma unroll
            for (int r = 0; r < 4; ++r) {
                int rr = orow + r;
                if (rr < N) zcat[(size_t)rr * 256 + col] = (__bf16)acc[ct][r];
            }
        }
    }
}

// ---------------------------------------------------------------------------
// Kernel 4: out[v] = relu( z1[v] + sum_e w_e * y2[src_e] + bias ), fp32.
// One wave per node. Lanes: g=lane>>4 edge-subgroup (4 edges per gather
// instruction), c=lane&15 feature chunk (bf16x8 = 16B per lane). Body
// unrolled x2 -> 8 edges in flight. Predicated weights kill the tail.
// shfl_xor butterfly (lane bits 4,5) merges the 4 edge-groups.
// ---------------------------------------------------------------------------
__global__ __launch_bounds__(256) void agg_out(
    const __bf16* __restrict__ zcat,   // [N,256] bf16
    const int* __restrict__ esrc,      // [E]
    const float* __restrict__ ew,      // [E] fp32
    const int* __restrict__ rowptr,    // [N+1]
    const float* __restrict__ bias,    // [128] fp32
    float* __restrict__ out,           // [N,128] fp32
    int N) {
    int wave = threadIdx.x >> 6;
    int lane = threadIdx.x & 63;
    int v = blockIdx.x * 4 + wave;
    if (v >= N) return;
    int g = lane >> 4;
    int c = lane & 15;

    int e0 = rowptr[v], e1 = rowptr[v + 1];
    float acc[8];
#pragma unroll
    for (int j = 0; j < 8; ++j) acc[j] = 0.f;

    const __bf16* gbase = zcat + 128 + (c << 3);  // second half of row
    for (int base = e0; base < e1; base += 8) {
        int ea = base + g, eb = base + 4 + g;
        int eac = min(ea, e1 - 1), ebc = min(eb, e1 - 1);
        int sa = esrc[eac], sb = esrc[ebc];
        float wa = (ea < e1) ? ew[eac] : 0.f;
        float wb = (eb < e1) ? ew[ebc] : 0.f;
        bf16x8 pa = *(const bf16x8*)(gbase + (size_t)sa * 256);
        bf16x8 pb = *(const bf16x8*)(gbase + (size_t)sb * 256);
#pragma unroll
        for (int j = 0; j < 8; ++j)
            acc[j] += wa * (float)pa[j] + wb * (float)pb[j];
    }

    // butterfly across the 4 edge-groups (lane bits 4 and 5)
#pragma unroll
    for (int j = 0; j < 8; ++j) acc[j] += __shfl_xor(acc[j], 16, 64);
#pragma unroll
    for (int j = 0; j < 8; ++j) acc[j] += __shfl_xor(acc[j], 32, 64);

    // epilogue: self term + bias, relu, fp32 store (groups 0/1 write halves)
    bf16x8 z1 = *(const bf16x8*)(zcat + (size_t)v * 256 + (c << 3));
    const float* bp = bias + (c << 3);
    float r[8];
#pragma unroll
    for (int j = 0; j < 8; ++j)
        r[j] = fmaxf((float)z1[j] + acc[j] + bp[j], 0.f);

    float* op = out + (size_t)v * 128 + (c << 3);
    if (g == 0) {
        f32x4 s = {r[0], r[1], r[2], r[3]};
        *(f32x4*)op = s;
    } else if (g == 1) {
        f32x4 s = {r[4], r[5], r[6], r[7]};
        *(f32x4*)(op + 4) = s;
    }
}

// ---------------------------------------------------------------------------
extern "C" void kernel_launch(void* const* d_in, const int* in_sizes, int n_in,
                              void* d_out, int out_size, void* d_ws,
                              size_t ws_size, hipStream_t stream) {
    const float* x = (const float*)d_in[0];
    const int* esrc = (const int*)d_in[1];
    const int* edst = (const int*)d_in[2];
    const float* ew = (const float*)d_in[3];
    const float* w = (const float*)d_in[4];
    const float* bias = (const float*)d_in[5];
    float* out = (float*)d_out;

    int N = in_sizes[0] / NFEAT;
    int E = in_sizes[1];

    // workspace layout
    char* ws = (char*)d_ws;
    __bf16* zcat = (__bf16*)ws;  // N*256*2 = 25.6 MB
    size_t zcat_bytes = ((size_t)N * 256 * 2 + 255) & ~(size_t)255;
    __bf16* wsw = (__bf16*)(ws + zcat_bytes);        // 64 KB
    int* rowptr = (int*)(ws + zcat_bytes + 65536);   // (N+1)*4

    build_rowptr<<<(E + 255) / 256, 256, 0, stream>>>(edst, rowptr, E, N);
    swizzle_w<<<(2 * NFEAT * NFEAT) / 256, 256, 0, stream>>>(w, wsw);
    int ntiles = (N + 15) / 16;
    gemm_z<<<1024, 256, 0, stream>>>(x, wsw, zcat, N, ntiles);
    agg_out<<<(N + 3) / 4, 256, 0, stream>>>(zcat, esrc, ew, rowptr, bias, out,
                                             N);
}

// Round 7
// 131.720 us; speedup vs baseline: 1.4763x; 1.0654x over previous
//
#include <hip/hip_runtime.h>
#include <hip/hip_bf16.h>

#define NFEAT 128   // IN_FT == OUT_FT == 128

typedef __bf16 bf16x8 __attribute__((ext_vector_type(8)));
typedef float f32x4 __attribute__((ext_vector_type(4)));
typedef float f32x2v __attribute__((ext_vector_type(2)));

// decode 8 packed fp8 e4m3 (OCP on gfx950) -> 8 floats
static __device__ __forceinline__ void fp8x8_to_f32(uint2 p, float* o) {
    f32x2v a0 = __builtin_amdgcn_cvt_pk_f32_fp8(p.x, false);
    f32x2v a1 = __builtin_amdgcn_cvt_pk_f32_fp8(p.x, true);
    f32x2v a2 = __builtin_amdgcn_cvt_pk_f32_fp8(p.y, false);
    f32x2v a3 = __builtin_amdgcn_cvt_pk_f32_fp8(p.y, true);
    o[0] = a0[0]; o[1] = a0[1]; o[2] = a1[0]; o[3] = a1[1];
    o[4] = a2[0]; o[5] = a2[1]; o[6] = a3[0]; o[7] = a3[1];
}

// encode one float -> fp8 e4m3 byte (RNE; values here are << 448 so no sat)
static __device__ __forceinline__ unsigned char f32_to_fp8(float v) {
    int r = __builtin_amdgcn_cvt_pk_fp8_f32(v, v, 0, false);
    return (unsigned char)(r & 0xff);
}

// ---------------------------------------------------------------------------
// Kernel 1 (prep): blocks [0,EB) build CSR rowptr from sorted edge_dst;
// blocks [EB, EB+128) swizzle+split W (fp32 [256,128]) into bf16 MFMA-B
// layout for the fused x @ [W1 | W2] GEMM (K=128, 256 cols):
//   wsw[((k>>3)*256 + n)*8 + (k&7)] = bf16( n<128 ? W[k][n] : W[128+k][n-128] )
// ---------------------------------------------------------------------------
__global__ __launch_bounds__(256) void prep(const int* __restrict__ edst,
                                            int* __restrict__ rowptr,
                                            const float* __restrict__ w,
                                            __bf16* __restrict__ wsw,
                                            int E, int N, int EB) {
    int bid = blockIdx.x;
    if (bid < EB) {
        int e = bid * 256 + threadIdx.x;
        if (e >= E) return;
        int d = edst[e];
        int prev = (e == 0) ? -1 : edst[e - 1];
        for (int v = prev + 1; v <= d; ++v) rowptr[v] = e;
        if (e == E - 1)
            for (int v = d + 1; v <= N; ++v) rowptr[v] = E;
    } else {
        int idx = (bid - EB) * 256 + threadIdx.x;  // 0..32767
        int k = idx >> 8, n = idx & 255;
        int row = (n < 128) ? k : 128 + k;
        int col = n & 127;
        wsw[(((k >> 3) * 256 + n) << 3) + (k & 7)] = (__bf16)w[row * 128 + col];
    }
}

// ---------------------------------------------------------------------------
// Kernel 2: z1 = bf16(x@W1 + bias)  [N,128],  z2 = fp8(x@W2)  [N,128].
// Register-resident B (wave = 64-col quarter, 64 VGPR); the block's 4 waves
// cover all 256 cols of ONE 16-row tile; grid-stride over tiles.
// A cast fp32->bf16 in-register. No LDS, no barriers.
// ---------------------------------------------------------------------------
__global__ __launch_bounds__(256, 2) void gemm_z(
    const float* __restrict__ x,      // [N,128] fp32
    const __bf16* __restrict__ wsw,   // swizzled [128,256] bf16
    const float* __restrict__ bias,   // [128] fp32
    __bf16* __restrict__ z1,          // [N,128] bf16 out (bias folded)
    unsigned char* __restrict__ z2,   // [N,128] fp8 out
    int N, int ntiles) {
    int t = threadIdx.x;
    int q = t >> 6;          // wave = column quarter
    int lane = t & 63;
    int m = lane & 15;
    int quad = lane >> 4;
    int colbase = q * 64 + m;

    bf16x8 B[4][4];  // [kstep][coltile] : 64 VGPRs
#pragma unroll
    for (int ks = 0; ks < 4; ++ks)
#pragma unroll
        for (int ct = 0; ct < 4; ++ct)
            B[ks][ct] = *(const bf16x8*)(wsw +
                (((size_t)(ks * 4 + quad) * 256 + colbase + ct * 16) << 3));

    float bi[4];
#pragma unroll
    for (int ct = 0; ct < 4; ++ct)
        bi[ct] = (q < 2) ? bias[colbase + ct * 16] : 0.f;

    for (int tile = blockIdx.x; tile < ntiles; tile += gridDim.x) {
        int row = tile * 16 + m;
        int rowc = min(row, N - 1);
        bf16x8 A[4];
#pragma unroll
        for (int ks = 0; ks < 4; ++ks) {
            const float* ap = x + (size_t)rowc * 128 + ks * 32 + quad * 8;
            f32x4 lo = *(const f32x4*)ap;
            f32x4 hi = *(const f32x4*)(ap + 4);
            bf16x8 af;
#pragma unroll
            for (int j = 0; j < 4; ++j) {
                af[j] = (__bf16)lo[j];
                af[j + 4] = (__bf16)hi[j];
            }
            A[ks] = af;
        }

        f32x4 acc[4];
#pragma unroll
        for (int ct = 0; ct < 4; ++ct) acc[ct] = (f32x4)(0.f);
#pragma unroll
        for (int ks = 0; ks < 4; ++ks)
#pragma unroll
            for (int ct = 0; ct < 4; ++ct)
                acc[ct] = __builtin_amdgcn_mfma_f32_16x16x32_bf16(
                    A[ks], B[ks][ct], acc[ct], 0, 0, 0);

        int orow = tile * 16 + quad * 4;  // D: col=lane&15, row=quad*4+r
        if (q < 2) {
#pragma unroll
            for (int ct = 0; ct < 4; ++ct) {
                int col = colbase + ct * 16;
#pragma unroll
                for (int r = 0; r < 4; ++r) {
                    int rr = orow + r;
                    if (rr < N)
                        z1[(size_t)rr * 128 + col] =
                            (__bf16)(acc[ct][r] + bi[ct]);
                }
            }
        } else {
#pragma unroll
            for (int ct = 0; ct < 4; ++ct) {
                int col = colbase + ct * 16 - 128;
#pragma unroll
                for (int r = 0; r < 4; ++r) {
                    int rr = orow + r;
                    if (rr < N)
                        z2[(size_t)rr * 128 + col] = f32_to_fp8(acc[ct][r]);
                }
            }
        }
    }
}

// ---------------------------------------------------------------------------
// Kernel 3: out[v] = relu( z1[v] + sum_e w_e * z2[src_e] ), fp32.
// One wave per node. g=lane>>4 edge-subgroup (4 edges per gather instr),
// c=lane&15 feature chunk (8 fp8 = 8 B per lane). Body unrolled x2 -> 8
// edges in flight; predicated weights (clamped dup loads hit L1) kill tail.
// shfl_xor butterfly (lane bits 4,5) merges the 4 edge-groups.
// ---------------------------------------------------------------------------
__global__ __launch_bounds__(256) void agg_out(
    const __bf16* __restrict__ z1,          // [N,128] bf16 (bias folded)
    const unsigned char* __restrict__ z2,   // [N,128] fp8
    const int* __restrict__ esrc,           // [E]
    const float* __restrict__ ew,           // [E] fp32
    const int* __restrict__ rowptr,         // [N+1]
    float* __restrict__ out,                // [N,128] fp32
    int N) {
    int wave = threadIdx.x >> 6;
    int lane = threadIdx.x & 63;
    int v = blockIdx.x * 4 + wave;
    if (v >= N) return;
    int g = lane >> 4;
    int c = lane & 15;

    int e0 = rowptr[v], e1 = rowptr[v + 1];
    float acc[8];
#pragma unroll
    for (int j = 0; j < 8; ++j) acc[j] = 0.f;

    const unsigned char* gbase = z2 + (c << 3);
    for (int base = e0; base < e1; base += 8) {
        int ea = base + g, eb = base + 4 + g;
        int eac = min(ea, e1 - 1), ebc = min(eb, e1 - 1);
        int sa = esrc[eac], sb = esrc[ebc];
        float wa = (ea < e1) ? ew[eac] : 0.f;
        float wb = (eb < e1) ? ew[ebc] : 0.f;
        uint2 pa = *(const uint2*)(gbase + (size_t)sa * 128);
        uint2 pb = *(const uint2*)(gbase + (size_t)sb * 128);
        float fa[8], fb[8];
        fp8x8_to_f32(pa, fa);
        fp8x8_to_f32(pb, fb);
#pragma unroll
        for (int j = 0; j < 8; ++j) acc[j] += wa * fa[j] + wb * fb[j];
    }

    // butterfly across the 4 edge-groups (lane bits 4 and 5)
#pragma unroll
    for (int j = 0; j < 8; ++j) acc[j] += __shfl_xor(acc[j], 16, 64);
#pragma unroll
    for (int j = 0; j < 8; ++j) acc[j] += __shfl_xor(acc[j], 32, 64);

    // epilogue: self term (bias already folded), relu, fp32 store
    bf16x8 s1 = *(const bf16x8*)(z1 + (size_t)v * 128 + (c << 3));
    float r[8];
#pragma unroll
    for (int j = 0; j < 8; ++j)
        r[j] = fmaxf((float)s1[j] + acc[j], 0.f);

    float* op = out + (size_t)v * 128 + (c << 3);
    if (g == 0) {
        f32x4 s = {r[0], r[1], r[2], r[3]};
        *(f32x4*)op = s;
    } else if (g == 1) {
        f32x4 s = {r[4], r[5], r[6], r[7]};
        *(f32x4*)(op + 4) = s;
    }
}

// ---------------------------------------------------------------------------
extern "C" void kernel_launch(void* const* d_in, const int* in_sizes, int n_in,
                              void* d_out, int out_size, void* d_ws,
                              size_t ws_size, hipStream_t stream) {
    const float* x = (const float*)d_in[0];
    const int* esrc = (const int*)d_in[1];
    const int* edst = (const int*)d_in[2];
    const float* ew = (const float*)d_in[3];
    const float* w = (const float*)d_in[4];
    const float* bias = (const float*)d_in[5];
    float* out = (float*)d_out;

    int N = in_sizes[0] / NFEAT;
    int E = in_sizes[1];

    // workspace layout
    char* ws = (char*)d_ws;
    __bf16* z1 = (__bf16*)ws;  // N*128*2 = 12.8 MB
    size_t z1_bytes = ((size_t)N * 128 * 2 + 255) & ~(size_t)255;
    unsigned char* z2 = (unsigned char*)(ws + z1_bytes);  // N*128 = 6.4 MB
    size_t z2_bytes = ((size_t)N * 128 + 255) & ~(size_t)255;
    __bf16* wsw = (__bf16*)(ws + z1_bytes + z2_bytes);    // 64 KB
    int* rowptr = (int*)(ws + z1_bytes + z2_bytes + 65536);

    int EB = (E + 255) / 256;
    prep<<<EB + 128, 256, 0, stream>>>(edst, rowptr, w, wsw, E, N, EB);
    int ntiles = (N + 15) / 16;
    gemm_z<<<1024, 256, 0, stream>>>(x, wsw, bias, z1, z2, N, ntiles);
    agg_out<<<(N + 3) / 4, 256, 0, stream>>>(z1, z2, esrc, ew, rowptr, out, N);
}

// Round 8
// 129.184 us; speedup vs baseline: 1.5052x; 1.0196x over previous
//
#include <hip/hip_runtime.h>
#include <hip/hip_bf16.h>

#define NFEAT 128   // IN_FT == OUT_FT == 128

typedef __bf16 bf16x8 __attribute__((ext_vector_type(8)));
typedef float f32x4 __attribute__((ext_vector_type(4)));
typedef float f32x2v __attribute__((ext_vector_type(2)));

// decode 8 packed fp8 e4m3 (OCP on gfx950) -> 8 floats
static __device__ __forceinline__ void fp8x8_to_f32(uint2 p, float* o) {
    f32x2v a0 = __builtin_amdgcn_cvt_pk_f32_fp8(p.x, false);
    f32x2v a1 = __builtin_amdgcn_cvt_pk_f32_fp8(p.x, true);
    f32x2v a2 = __builtin_amdgcn_cvt_pk_f32_fp8(p.y, false);
    f32x2v a3 = __builtin_amdgcn_cvt_pk_f32_fp8(p.y, true);
    o[0] = a0[0]; o[1] = a0[1]; o[2] = a1[0]; o[3] = a1[1];
    o[4] = a2[0]; o[5] = a2[1]; o[6] = a3[0]; o[7] = a3[1];
}

// encode one float -> fp8 e4m3 byte (RNE; |v| << 448 here so no saturation)
static __device__ __forceinline__ unsigned char f32_to_fp8(float v) {
    int r = __builtin_amdgcn_cvt_pk_fp8_f32(v, v, 0, false);
    return (unsigned char)(r & 0xff);
}

// ---------------------------------------------------------------------------
// Dispatch 1: blocks [0,GB) compute z1 = bf16(x@W1 + bias), z2 = fp8(x@W2);
// blocks [GB, GB+EB) build CSR rowptr from sorted edge_dst (only needed by
// dispatch 2, so it can ride along here).
// GEMM: register-resident B built straight from raw fp32 W (one-time 128
// coalesced L2-hit loads per wave; no swizzle pass, no LDS, no barriers).
// Wave q = 64-col quarter of [W1|W2]; 4 waves cover one 16-row tile.
// ---------------------------------------------------------------------------
__global__ __launch_bounds__(256, 2) void gemm_z(
    const float* __restrict__ x,      // [N,128] fp32
    const float* __restrict__ w,      // [256,128] fp32 (raw)
    const float* __restrict__ bias,   // [128] fp32
    const int* __restrict__ edst,     // [E] sorted
    int* __restrict__ rowptr,         // [N+1] out
    __bf16* __restrict__ z1,          // [N,128] bf16 out (bias folded)
    unsigned char* __restrict__ z2,   // [N,128] fp8 out
    int N, int E, int ntiles, int GB) {
    if ((int)blockIdx.x >= GB) {
        // ---- CSR rowptr builder ----
        int e = ((int)blockIdx.x - GB) * 256 + threadIdx.x;
        if (e >= E) return;
        int d = edst[e];
        int prev = (e == 0) ? -1 : edst[e - 1];
        for (int v = prev + 1; v <= d; ++v) rowptr[v] = e;
        if (e == E - 1)
            for (int v = d + 1; v <= N; ++v) rowptr[v] = E;
        return;
    }

    int t = threadIdx.x;
    int q = t >> 6;          // wave = column quarter of [W1|W2]
    int lane = t & 63;
    int m = lane & 15;
    int quad = lane >> 4;
    int nloc = (q & 1) * 64 + m;    // col within the 128-wide half (+ct*16)
    int rbase = (q < 2) ? 0 : 128;  // W1 rows 0..127, W2 rows 128..255

    // B fragments from raw W: frag elem j = W[rbase + ks*32+quad*8+j][col]
    bf16x8 B[4][4];
#pragma unroll
    for (int ks = 0; ks < 4; ++ks)
#pragma unroll
        for (int ct = 0; ct < 4; ++ct) {
            bf16x8 f;
#pragma unroll
            for (int j = 0; j < 8; ++j)
                f[j] = (__bf16)w[(size_t)(rbase + ks * 32 + quad * 8 + j) * 128
                                 + nloc + ct * 16];
            B[ks][ct] = f;
        }

    float bi[4];
#pragma unroll
    for (int ct = 0; ct < 4; ++ct)
        bi[ct] = (q < 2) ? bias[nloc + ct * 16] : 0.f;

    for (int tile = blockIdx.x; tile < ntiles; tile += GB) {
        int row = tile * 16 + m;
        int rowc = min(row, N - 1);
        bf16x8 A[4];
#pragma unroll
        for (int ks = 0; ks < 4; ++ks) {
            const float* ap = x + (size_t)rowc * 128 + ks * 32 + quad * 8;
            f32x4 lo = *(const f32x4*)ap;
            f32x4 hi = *(const f32x4*)(ap + 4);
            bf16x8 af;
#pragma unroll
            for (int j = 0; j < 4; ++j) {
                af[j] = (__bf16)lo[j];
                af[j + 4] = (__bf16)hi[j];
            }
            A[ks] = af;
        }

        f32x4 acc[4];
#pragma unroll
        for (int ct = 0; ct < 4; ++ct) acc[ct] = (f32x4)(0.f);
#pragma unroll
        for (int ks = 0; ks < 4; ++ks)
#pragma unroll
            for (int ct = 0; ct < 4; ++ct)
                acc[ct] = __builtin_amdgcn_mfma_f32_16x16x32_bf16(
                    A[ks], B[ks][ct], acc[ct], 0, 0, 0);

        int orow = tile * 16 + quad * 4;  // D: col=lane&15, row=quad*4+r
        if (q < 2) {
#pragma unroll
            for (int ct = 0; ct < 4; ++ct) {
                int col = nloc + ct * 16;
#pragma unroll
                for (int r = 0; r < 4; ++r) {
                    int rr = orow + r;
                    if (rr < N)
                        z1[(size_t)rr * 128 + col] =
                            (__bf16)(acc[ct][r] + bi[ct]);
                }
            }
        } else {
#pragma unroll
            for (int ct = 0; ct < 4; ++ct) {
                int col = nloc + ct * 16;
#pragma unroll
                for (int r = 0; r < 4; ++r) {
                    int rr = orow + r;
                    if (rr < N)
                        z2[(size_t)rr * 128 + col] = f32_to_fp8(acc[ct][r]);
                }
            }
        }
    }
}

// ---------------------------------------------------------------------------
// Dispatch 2: out[v] = relu( z1[v] + sum_e w_e * z2[src_e] ), fp32.
// One wave per node. Edge metadata for the whole node loaded ONCE coalesced
// (lane l <- edge e0+l, deg<=64 fast path), then broadcast via __shfl.
// Inner body: 16 edges/iter = 4 independent 8B-gathers per feature-lane
// group (g=lane>>4), weight-0 predication (inactive groups hit L1-hot row 0).
// shfl_xor butterfly (lane bits 4,5) merges the 4 edge-groups.
// ---------------------------------------------------------------------------
__global__ __launch_bounds__(256) void agg_out(
    const __bf16* __restrict__ z1,          // [N,128] bf16 (bias folded)
    const unsigned char* __restrict__ z2,   // [N,128] fp8
    const int* __restrict__ esrc,           // [E]
    const float* __restrict__ ew,           // [E] fp32
    const int* __restrict__ rowptr,         // [N+1]
    float* __restrict__ out,                // [N,128] fp32
    int N) {
    int wave = threadIdx.x >> 6;
    int lane = threadIdx.x & 63;
    int v = blockIdx.x * 4 + wave;
    if (v >= N) return;
    int g = lane >> 4;
    int c = lane & 15;

    int e0 = rowptr[v], e1 = rowptr[v + 1];
    int deg = e1 - e0;

    // coalesced per-node metadata: lane l holds edge e0+l
    int myе_guard = e0 + lane;
    int s_l = 0;
    float w_l = 0.f;
    if (myе_guard < e1) {
        s_l = esrc[myе_guard];
        w_l = ew[myе_guard];
    }

    float acc[8];
#pragma unroll
    for (int j = 0; j < 8; ++j) acc[j] = 0.f;

    const unsigned char* gbase = z2 + (c << 3);
    int dmax = (deg < 64) ? deg : 64;
    for (int base = 0; base < dmax; base += 16) {
        int ss[4];
        float ww[4];
        uint2 p[4];
#pragma unroll
        for (int u = 0; u < 4; ++u) {
            int idx = base + u * 4 + g;      // edge slot (lane) to broadcast
            ss[u] = __shfl(s_l, idx);
            ww[u] = __shfl(w_l, idx);        // 0 beyond deg
            p[u] = *(const uint2*)(gbase + (size_t)ss[u] * 128);
        }
#pragma unroll
        for (int u = 0; u < 4; ++u) {
            float f[8];
            fp8x8_to_f32(p[u], f);
#pragma unroll
            for (int j = 0; j < 8; ++j) acc[j] += ww[u] * f[j];
        }
    }
    // rare overflow path (deg > 64)
    for (int bb = e0 + 64; bb < e1; bb += 4) {
        int ee = bb + g;
        int eec = min(ee, e1 - 1);
        int ss = esrc[eec];
        float ww = (ee < e1) ? ew[eec] : 0.f;
        uint2 p = *(const uint2*)(gbase + (size_t)ss * 128);
        float f[8];
        fp8x8_to_f32(p, f);
#pragma unroll
        for (int j = 0; j < 8; ++j) acc[j] += ww * f[j];
    }

    // butterfly across the 4 edge-groups (lane bits 4 and 5)
#pragma unroll
    for (int j = 0; j < 8; ++j) acc[j] += __shfl_xor(acc[j], 16, 64);
#pragma unroll
    for (int j = 0; j < 8; ++j) acc[j] += __shfl_xor(acc[j], 32, 64);

    // epilogue: self term (bias folded into z1), relu, fp32 store
    bf16x8 s1 = *(const bf16x8*)(z1 + (size_t)v * 128 + (c << 3));
    float r[8];
#pragma unroll
    for (int j = 0; j < 8; ++j)
        r[j] = fmaxf((float)s1[j] + acc[j], 0.f);

    float* op = out + (size_t)v * 128 + (c << 3);
    if (g == 0) {
        f32x4 s = {r[0], r[1], r[2], r[3]};
        *(f32x4*)op = s;
    } else if (g == 1) {
        f32x4 s = {r[4], r[5], r[6], r[7]};
        *(f32x4*)(op + 4) = s;
    }
}

// ---------------------------------------------------------------------------
extern "C" void kernel_launch(void* const* d_in, const int* in_sizes, int n_in,
                              void* d_out, int out_size, void* d_ws,
                              size_t ws_size, hipStream_t stream) {
    const float* x = (const float*)d_in[0];
    const int* esrc = (const int*)d_in[1];
    const int* edst = (const int*)d_in[2];
    const float* ew = (const float*)d_in[3];
    const float* w = (const float*)d_in[4];
    const float* bias = (const float*)d_in[5];
    float* out = (float*)d_out;

    int N = in_sizes[0] / NFEAT;
    int E = in_sizes[1];

    // workspace layout
    char* ws = (char*)d_ws;
    __bf16* z1 = (__bf16*)ws;  // N*128*2 = 12.8 MB
    size_t z1_bytes = ((size_t)N * 128 * 2 + 255) & ~(size_t)255;
    unsigned char* z2 = (unsigned char*)(ws + z1_bytes);  // N*128 = 6.4 MB
    size_t z2_bytes = ((size_t)N * 128 + 255) & ~(size_t)255;
    int* rowptr = (int*)(ws + z1_bytes + z2_bytes);       // (N+1)*4

    int ntiles = (N + 15) / 16;
    int GB = 1024;                    // gemm blocks
    int EB = (E + 255) / 256;         // rowptr-builder blocks
    gemm_z<<<GB + EB, 256, 0, stream>>>(x, w, bias, edst, rowptr, z1, z2, N, E,
                                        ntiles, GB);
    agg_out<<<(N + 3) / 4, 256, 0, stream>>>(z1, z2, esrc, ew, rowptr, out, N);
}